// Round 1
// 1458.422 us; speedup vs baseline: 1.1586x; 1.1586x over previous
//
#include <hip/hip_runtime.h>
#include <cstdint>
#include <cstddef>

typedef unsigned short u16;
typedef __attribute__((ext_vector_type(8))) short short8;
typedef __attribute__((ext_vector_type(4))) float f32x4;

#define MI_N  2048
#define DIS_N 1024
#define TOT_N 3072
#define DIN   3072
#define HID   256
#define LL    15
#define NG    8

__device__ __forceinline__ float b2f(u16 u) {
  unsigned int v = ((unsigned int)u) << 16;
  float f;
  __builtin_memcpy(&f, &v, 4);
  return f;
}
__device__ __forceinline__ u16 f2b(float f) {
  unsigned int u;
  __builtin_memcpy(&u, &f, 4);
  u = (u + 0x7fffu + ((u >> 16) & 1u)) >> 16;  // RTNE
  return (u16)u;
}
__device__ __forceinline__ float sigf(float x) { return 1.f / (1.f + __expf(-x)); }

// ---------------------------------------------------------------------------
// Batched f32 -> bf16 conversion. All segment counts are multiples of 2048.
// ---------------------------------------------------------------------------
#define NSEG 20
struct CvtJobs {
  const float* src[NSEG];
  u16* dst[NSEG];
  int nblk[NSEG];
  int nseg;
};

__global__ __launch_bounds__(256) void cvt_f2b(CvtJobs j) {
  int b = blockIdx.x, s = 0;
  while (s + 1 < j.nseg && b >= j.nblk[s]) { b -= j.nblk[s]; ++s; }
  const long base = ((long)b * 256 + threadIdx.x) * 8;
  const float4 v0 = *(const float4*)(j.src[s] + base);
  const float4 v1 = *(const float4*)(j.src[s] + base + 4);
  short8 o;
  o[0] = (short)f2b(v0.x); o[1] = (short)f2b(v0.y);
  o[2] = (short)f2b(v0.z); o[3] = (short)f2b(v0.w);
  o[4] = (short)f2b(v1.x); o[5] = (short)f2b(v1.y);
  o[6] = (short)f2b(v1.z); o[7] = (short)f2b(v1.w);
  *(short8*)(j.dst[s] + base) = o;
}

// ---------------------------------------------------------------------------
// Generic MFMA GEMM: C = act(A @ B^T + bias).
// A [M,K] bf16 row-major, B [N,K] bf16 row-major.
// 4 waves/block (256 thr): wave w processes kk = w*32 + 128*t (K-interleave),
// then staged LDS reduction (deterministic order), wave 0 does the epilogue.
// 32 rows x 16*NCT cols per block. Two parameter sets selected by blockIdx.x.
// ---------------------------------------------------------------------------
struct GP {
  const u16* A; int lda;
  const u16* B; int ldb;
  void* C; int ldc;
  const float* bias;
  int K;
  int mblk;
};

template <int ACT, int TRANS, int F32OUT, int NCT>
__global__ __launch_bounds__(256) void gemm_bt(GP p0, GP p1) {
  GP p = p0;
  int bx = blockIdx.x;
  if (bx >= p0.mblk) { bx -= p0.mblk; p = p1; }
  const int tid = threadIdx.x;
  const int w = tid >> 6;
  const int lane = tid & 63;
  const int m16 = lane & 15, quad = lane >> 4;
  const int kph = quad * 8;
  const long row0 = (long)bx * 32 + m16;
  const long colBase = (long)blockIdx.y * (16 * NCT);
  f32x4 acc[2][NCT] = {};
  const u16* A0 = p.A + row0 * (long)p.lda + kph;
  const u16* A1 = A0 + 16L * p.lda;
  const u16* Bb = p.B + (colBase + m16) * (long)p.ldb + kph;
  const long bstep = 16L * p.ldb;
  for (int kk = w * 32; kk < p.K; kk += 128) {
    short8 a0 = *(const short8*)(A0 + kk);
    short8 a1 = *(const short8*)(A1 + kk);
#pragma unroll
    for (int c = 0; c < NCT; ++c) {
      short8 b = *(const short8*)(Bb + c * bstep + kk);
      acc[0][c] = __builtin_amdgcn_mfma_f32_16x16x32_bf16(a0, b, acc[0][c], 0, 0, 0);
      acc[1][c] = __builtin_amdgcn_mfma_f32_16x16x32_bf16(a1, b, acc[1][c], 0, 0, 0);
    }
  }
  // Staged cross-wave reduction. +1 pad -> bank = (lane + i) % 32, conflict-free.
  __shared__ float red[2][64][NCT * 8 + 1];
  float* av = (float*)acc;  // 2*NCT*4 contiguous floats
  if (w >= 2) {
#pragma unroll
    for (int i = 0; i < NCT * 8; ++i) red[w - 2][lane][i] = av[i];
  }
  __syncthreads();
  if (w < 2) {
#pragma unroll
    for (int i = 0; i < NCT * 8; ++i) av[i] += red[w][lane][i];
  }
  __syncthreads();
  if (w == 1) {
#pragma unroll
    for (int i = 0; i < NCT * 8; ++i) red[0][lane][i] = av[i];
  }
  __syncthreads();
  if (w != 0) return;
#pragma unroll
  for (int i = 0; i < NCT * 8; ++i) av[i] += red[0][lane][i];
#pragma unroll
  for (int c = 0; c < NCT; ++c) {
    const long col = colBase + c * 16 + m16;
    const float bv = p.bias ? p.bias[col] : 0.f;
#pragma unroll
    for (int r = 0; r < 2; ++r) {
      const long orow = (long)bx * 32 + r * 16 + quad * 4;
#pragma unroll
      for (int j = 0; j < 4; ++j) {
        float v = acc[r][c][j] + bv;
        if (ACT == 1) v = fmaxf(v, 0.f);
        if (ACT == 2) v = sigf(v);
        if (F32OUT)
          ((float*)p.C)[(orow + j) * (long)p.ldc + col] = v;
        else if (TRANS)
          ((u16*)p.C)[col * (long)p.ldc + orow + j] = f2b(v);
        else
          ((u16*)p.C)[(orow + j) * (long)p.ldc + col] = f2b(v);
      }
    }
  }
}

// ---------------------------------------------------------------------------
// FastKAN fused GEMM. Basis A-fragments generated in-register (lane's 8
// k-elements == the 8 gaussians of one input dim d). K split over blockIdx.z:
// chunks 0..3 = basis K (6144 each of 24576), chunk 4 = silu(x) @ Wb^T
// (K=3072). 4 waves/block with K-interleave + staged LDS reduction.
// f32 partials -> fk_combine.
// ---------------------------------------------------------------------------
struct FKP {
  const u16* xn; const u16* xb;
  const u16* Ws; const u16* Wb;
  float* partial;
  int rowoff;
  int mblk;
};

__global__ __launch_bounds__(256) void fastkan_gemm(FKP p0, FKP p1, const float* grid8) {
  FKP p = p0;
  int bx = blockIdx.x;
  if (bx >= p0.mblk) { bx -= p0.mblk; p = p1; }
  const int chunk = blockIdx.z;
  const int tid = threadIdx.x;
  const int w = tid >> 6;
  const int lane = tid & 63;
  const int m16 = lane & 15, quad = lane >> 4, kph = quad * 8;
  const long row0 = (long)bx * 32 + m16;
  const long colBase = (long)blockIdx.y * 128;  // NCT=8
  f32x4 acc[2][8] = {};
  if (chunk < 4) {
    float gv[8];
#pragma unroll
    for (int j = 0; j < 8; ++j) gv[j] = grid8[j];
    const u16* xn0 = p.xn + row0 * (long)DIN;
    const u16* xn1 = xn0 + 16L * DIN;
    const int k0 = chunk * 6144, k1 = k0 + 6144;
    for (int kk = k0 + w * 32; kk < k1; kk += 128) {
      const int d = (kk >> 3) + quad;
      const float x0 = b2f(xn0[d]);
      const float x1 = b2f(xn1[d]);
      short8 a0, a1;
#pragma unroll
      for (int j = 0; j < 8; ++j) {
        float t0 = (x0 - gv[j]) * 1.75f;  // /DENOM, DENOM = 4/7
        float t1 = (x1 - gv[j]) * 1.75f;
        a0[j] = (short)f2b(__expf(-t0 * t0));
        a1[j] = (short)f2b(__expf(-t1 * t1));
      }
#pragma unroll
      for (int c = 0; c < 8; ++c) {
        const u16* Bp = p.Ws + (colBase + c * 16 + m16) * (long)(DIN * NG) + kk + kph;
        short8 b = *(const short8*)Bp;
        acc[0][c] = __builtin_amdgcn_mfma_f32_16x16x32_bf16(a0, b, acc[0][c], 0, 0, 0);
        acc[1][c] = __builtin_amdgcn_mfma_f32_16x16x32_bf16(a1, b, acc[1][c], 0, 0, 0);
      }
    }
  } else {
    const u16* x0p = p.xb + row0 * (long)DIN + kph;
    const u16* x1p = x0p + 16L * DIN;
    for (int kk = w * 32; kk < DIN; kk += 128) {
      short8 r0 = *(const short8*)(x0p + kk);
      short8 r1 = *(const short8*)(x1p + kk);
      short8 a0, a1;
#pragma unroll
      for (int j = 0; j < 8; ++j) {
        float v0 = b2f((u16)r0[j]);
        float v1 = b2f((u16)r1[j]);
        a0[j] = (short)f2b(v0 * sigf(v0));
        a1[j] = (short)f2b(v1 * sigf(v1));
      }
#pragma unroll
      for (int c = 0; c < 8; ++c) {
        const u16* Bp = p.Wb + (colBase + c * 16 + m16) * (long)DIN + kk + kph;
        short8 b = *(const short8*)Bp;
        acc[0][c] = __builtin_amdgcn_mfma_f32_16x16x32_bf16(a0, b, acc[0][c], 0, 0, 0);
        acc[1][c] = __builtin_amdgcn_mfma_f32_16x16x32_bf16(a1, b, acc[1][c], 0, 0, 0);
      }
    }
  }
  // Staged cross-wave reduction (deterministic order; +1 pad -> conflict-free).
  __shared__ float red[2][64][65];
  float* av = (float*)acc;  // 64 contiguous floats
  if (w >= 2) {
#pragma unroll
    for (int i = 0; i < 64; ++i) red[w - 2][lane][i] = av[i];
  }
  __syncthreads();
  if (w < 2) {
#pragma unroll
    for (int i = 0; i < 64; ++i) av[i] += red[w][lane][i];
  }
  __syncthreads();
  if (w == 1) {
#pragma unroll
    for (int i = 0; i < 64; ++i) red[0][lane][i] = av[i];
  }
  __syncthreads();
  if (w != 0) return;
#pragma unroll
  for (int i = 0; i < 64; ++i) av[i] += red[0][lane][i];
  float* outp = p.partial + ((long)chunk * TOT_N + p.rowoff) * HID;
#pragma unroll
  for (int c = 0; c < 8; ++c) {
    const long col = colBase + c * 16 + m16;
#pragma unroll
    for (int r = 0; r < 2; ++r) {
      const long orow = (long)bx * 32 + r * 16 + quad * 4;
#pragma unroll
      for (int j = 0; j < 4; ++j) outp[(orow + j) * HID + col] = acc[r][c][j];
    }
  }
}

__global__ __launch_bounds__(256) void fk_combine(const float* partial, const float* bb_mi,
                                                  const float* bb_dis, u16* e) {
  const long i = (long)blockIdx.x * 256 + threadIdx.x;
  const int c = (int)(i & 255);
  const long n = i >> 8;
  float s = 0.f;
#pragma unroll
  for (int pI = 0; pI < 5; ++pI) s += partial[(long)pI * TOT_N * HID + i];
  s += (n < MI_N ? bb_mi : bb_dis)[c];
  e[i] = f2b(s);
}

// ---------------------------------------------------------------------------
// W_eff: outT[s][l][o][i] = sum_h a_h W[l,h,i,o] / 8  (f32 in, bf16 out)
// ---------------------------------------------------------------------------
__global__ __launch_bounds__(256) void weff_kernel(const float* Wmi, const float* Ami,
                                                   const float* Wdis, const float* Adis,
                                                   u16* outT) {
  const int b = blockIdx.x;  // 2*15*256
  const int s = b / 3840;
  const int r = b % 3840;
  const int l = r >> 8;
  const int t = r & 255;
  const int i0 = (t >> 4) << 4;
  const int o0 = (t & 15) << 4;
  const float* W = (s ? Wdis : Wmi) + (long)l * 8 * 65536;
  const float* A = (s ? Adis : Ami) + l * 8;
  const int tx = threadIdx.x & 15;  // o within tile
  const int ty = threadIdx.x >> 4;  // i within tile
  float sum = 0.f;
#pragma unroll
  for (int h = 0; h < 8; ++h)
    sum += A[h] * W[(long)h * 65536 + (long)(i0 + ty) * 256 + o0 + tx];
  sum *= 0.125f;
  __shared__ float tile[16][17];
  tile[ty][tx] = sum;
  __syncthreads();
  outT[((long)s * LL + l) * 65536 + (long)(o0 + ty) * 256 + i0 + tx] = f2b(tile[tx][ty]);
}

// ---------------------------------------------------------------------------
__device__ __forceinline__ void breduce2(float& a, float& b) {
  for (int o = 32; o > 0; o >>= 1) {
    a += __shfl_down(a, o);
    b += __shfl_down(b, o);
  }
  __shared__ float sm[8];
  const int w = threadIdx.x >> 6;
  const int lane = threadIdx.x & 63;
  if (lane == 0) { sm[w] = a; sm[4 + w] = b; }
  __syncthreads();
  if (threadIdx.x == 0) {
    sm[0] = sm[0] + sm[1] + sm[2] + sm[3];
    sm[4] = sm[4] + sm[5] + sm[6] + sm[7];
  }
  __syncthreads();
  a = sm[0];
  b = sm[4];
}

// FastKAN pre: xn = bf16(LN(x)*g+b), cbf = bf16(x). One row per block.
__global__ __launch_bounds__(256) void ln_silu(const float* xmi, const float* xdis,
                                               const float* gmi, const float* bmi,
                                               const float* gdis, const float* bdis,
                                               u16* xn, u16* cbf) {
  const int n = blockIdx.x;  // 0..3071
  const bool ds = (n >= MI_N);
  const float* x = ds ? xdis + (long)(n - MI_N) * DIN : xmi + (long)n * DIN;
  const float* g = ds ? gdis : gmi;
  const float* be = ds ? bdis : bmi;
  float xv[12];
  float s1 = 0.f, s2 = 0.f;
#pragma unroll
  for (int j = 0; j < 12; ++j) {
    xv[j] = x[j * 256 + threadIdx.x];
    s1 += xv[j];
    s2 += xv[j] * xv[j];
  }
  breduce2(s1, s2);
  const float m = s1 * (1.f / DIN);
  const float inv = rsqrtf(s2 * (1.f / DIN) - m * m + 1e-5f);
#pragma unroll
  for (int j = 0; j < 12; ++j) {
    const int e = j * 256 + threadIdx.x;
    xn[(long)n * DIN + e] = f2b((xv[j] - m) * inv * g[e] + be[e]);
    cbf[(long)n * DIN + e] = f2b(xv[j]);
  }
}

// Per-layer epilogue: y = leaky025(LN(hout*gate)) -> jk slice l
__global__ __launch_bounds__(256) void gate_ln(const u16* hout, const u16* gate,
                                               const float* gmi, const float* bmi,
                                               const float* gdis, const float* bdis,
                                               u16* jk, int l) {
  const int n = blockIdx.x;
  const int c = threadIdx.x;
  const bool ds = (n >= MI_N);
  const float* g = (ds ? gdis : gmi) + l * HID;
  const float* be = (ds ? bdis : bmi) + l * HID;
  const float h = b2f(hout[(long)n * HID + c]) * b2f(gate[(long)n * HID + c]);
  float s1 = h, s2 = h * h;
  breduce2(s1, s2);
  const float m = s1 * (1.f / HID);
  const float var = s2 * (1.f / HID) - m * m;
  float y = (h - m) * rsqrtf(var + 1e-5f) * g[c] + be[c];
  y = (y >= 0.f) ? y : 0.25f * y;
  jk[(long)n * (LL * HID) + l * HID + c] = f2b(y);
}

// score = 0.7*sig(recon) + 0.3*sig(result_h). recon already in d_out[MI*DIS..].
__global__ __launch_bounds__(256) void final_combine(const float* rh, float* out) {
  const long i = (long)blockIdx.x * 256 + threadIdx.x;
  const float rc = out[(long)MI_N * DIS_N + i];
  out[i] = 0.7f * sigf(rc) + 0.3f * sigf(rh[i]);
}

// ---------------------------------------------------------------------------
extern "C" void kernel_launch(void* const* d_in, const int* in_sizes, int n_in,
                              void* d_out, int out_size, void* d_ws, size_t ws_size,
                              hipStream_t stream) {
  const float* concat_mi   = (const float*)d_in[0];
  const float* concat_dis  = (const float*)d_in[1];
  const float* G_mi        = (const float*)d_in[2];
  const float* G_dis       = (const float*)d_in[3];
  // d_in[4]=AT, d_in[5]=A unused
  const float* rbf_grid    = (const float*)d_in[6];
  const float* mi_kan_ln_g = (const float*)d_in[7];
  const float* mi_kan_ln_b = (const float*)d_in[8];
  const float* mi_kan_Ws   = (const float*)d_in[9];
  const float* mi_kan_Wb   = (const float*)d_in[10];
  const float* mi_kan_bb   = (const float*)d_in[11];
  const float* mi_W        = (const float*)d_in[12];
  const float* mi_attn     = (const float*)d_in[13];
  const float* mi_bias     = (const float*)d_in[14];
  const float* mi_rW1      = (const float*)d_in[15];
  const float* mi_rb1      = (const float*)d_in[16];
  const float* mi_rW2      = (const float*)d_in[17];
  const float* mi_rb2      = (const float*)d_in[18];
  const float* mi_ln_g     = (const float*)d_in[19];
  const float* mi_ln_b     = (const float*)d_in[20];
  const float* mi_jk_W     = (const float*)d_in[21];
  const float* mi_jk_b     = (const float*)d_in[22];
  const float* dis_kan_ln_g = (const float*)d_in[23];
  const float* dis_kan_ln_b = (const float*)d_in[24];
  const float* dis_kan_Ws  = (const float*)d_in[25];
  const float* dis_kan_Wb  = (const float*)d_in[26];
  const float* dis_kan_bb  = (const float*)d_in[27];
  const float* dis_W       = (const float*)d_in[28];
  const float* dis_attn    = (const float*)d_in[29];
  const float* dis_bias    = (const float*)d_in[30];
  const float* dis_rW1     = (const float*)d_in[31];
  const float* dis_rb1     = (const float*)d_in[32];
  const float* dis_rW2     = (const float*)d_in[33];
  const float* dis_rb2     = (const float*)d_in[34];
  const float* dis_ln_g    = (const float*)d_in[35];
  const float* dis_ln_b    = (const float*)d_in[36];
  const float* dis_jk_W    = (const float*)d_in[37];
  const float* dis_jk_b    = (const float*)d_in[38];
  const float* lx_W1 = (const float*)d_in[39]; const float* lx_b1 = (const float*)d_in[40];
  const float* lx_W2 = (const float*)d_in[41]; const float* lx_b2 = (const float*)d_in[42];
  const float* lx_W3 = (const float*)d_in[43]; const float* lx_b3 = (const float*)d_in[44];
  const float* ly_W1 = (const float*)d_in[45]; const float* ly_b1 = (const float*)d_in[46];
  const float* ly_W2 = (const float*)d_in[47]; const float* ly_b2 = (const float*)d_in[48];
  const float* ly_W3 = (const float*)d_in[49]; const float* ly_b3 = (const float*)d_in[50];
  const float* ne_W  = (const float*)d_in[51]; const float* ne_b  = (const float*)d_in[52];
  const float* he_W  = (const float*)d_in[53]; const float* he_b  = (const float*)d_in[54];
  const float* mun_W = (const float*)d_in[55]; const float* mun_b = (const float*)d_in[56];
  const float* mue_W = (const float*)d_in[57]; const float* mue_b = (const float*)d_in[58];

  char* wp = (char*)d_ws;
  size_t off = 0;
  auto alloc = [&](size_t bytes) -> void* {
    void* p = wp + off;
    off += (bytes + 255) & ~(size_t)255;
    return p;
  };
  u16* cbf    = (u16*)alloc((size_t)TOT_N * DIN * 2);
  u16* gmib   = (u16*)alloc((size_t)MI_N * MI_N * 2);
  u16* gdisb  = (u16*)alloc((size_t)DIS_N * DIS_N * 2);
  u16* wsb0   = (u16*)alloc((size_t)256 * 24576 * 2);
  u16* wsb1   = (u16*)alloc((size_t)256 * 24576 * 2);
  u16* wbb0   = (u16*)alloc((size_t)256 * 3072 * 2);
  u16* wbb1   = (u16*)alloc((size_t)256 * 3072 * 2);
  u16* jkwb0  = (u16*)alloc((size_t)256 * 3840 * 2);
  u16* jkwb1  = (u16*)alloc((size_t)256 * 3840 * 2);
  u16* rw1b0  = (u16*)alloc((size_t)LL * 64 * 256 * 2);
  u16* rw1b1  = (u16*)alloc((size_t)LL * 64 * 256 * 2);
  u16* rw2b0  = (u16*)alloc((size_t)LL * 256 * 64 * 2);
  u16* rw2b1  = (u16*)alloc((size_t)LL * 256 * 64 * 2);
  u16* lxw1b  = (u16*)alloc((size_t)256 * 256 * 2);
  u16* lxw2b  = (u16*)alloc((size_t)128 * 256 * 2);
  u16* lxw3b  = (u16*)alloc((size_t)64 * 128 * 2);
  u16* lyw1b  = (u16*)alloc((size_t)256 * 256 * 2);
  u16* lyw2b  = (u16*)alloc((size_t)128 * 256 * 2);
  u16* lyw3b  = (u16*)alloc((size_t)64 * 128 * 2);
  u16* neb    = (u16*)alloc((size_t)512 * 3072 * 2);
  u16* heb    = (u16*)alloc((size_t)512 * 3072 * 2);
  u16* munb   = (u16*)alloc((size_t)64 * 512 * 2);
  u16* mueb   = (u16*)alloc((size_t)64 * 512 * 2);
  u16* wefft  = (u16*)alloc((size_t)2 * LL * 65536 * 2);
  u16* e      = (u16*)alloc((size_t)TOT_N * HID * 2);
  u16* t1t    = (u16*)alloc((size_t)HID * TOT_N * 2);
  u16* hout   = (u16*)alloc((size_t)TOT_N * HID * 2);
  u16* g1b    = (u16*)alloc((size_t)TOT_N * 64 * 2);
  u16* gateb  = (u16*)alloc((size_t)TOT_N * HID * 2);
  u16* jk     = (u16*)alloc((size_t)TOT_N * LL * HID * 2);
  u16* fb     = (u16*)alloc((size_t)TOT_N * HID * 2);
  // Region A: xn + fkp (fastkan phase) aliased with post-fastkan buffers
  char* regA  = (char*)alloc(35000000);
  u16* xn     = (u16*)regA;                              // 18,874,368 B
  float* fkp  = (float*)(regA + 18874624);               // 15,728,640 B
  u16* h1b    = (u16*)regA;                              // 1,572,864
  u16* h2b    = (u16*)(regA + 1572864);                  //   786,432
  u16* xyb    = (u16*)(regA + 2359296);                  //   393,216
  float* rh   = (float*)(regA + 2752512);                // 8,388,608
  u16* zb     = (u16*)(regA + 11141120);                 // 3,145,728
  u16* zm     = (u16*)(regA + 14286848);                 //   393,216
  float* outf = (float*)d_out;
  float* rec  = outf + (size_t)MI_N * DIS_N;             // recon written in place
  (void)ws_size; (void)in_sizes; (void)n_in; (void)out_size;

  const dim3 B256(256);

  // 0) f32 -> bf16 conversions (one launch, 20 segments)
  {
    CvtJobs cj{};
    int ns = 0, total = 0;
    auto push = [&](const float* s, u16* dst, int count) {
      cj.src[ns] = s; cj.dst[ns] = dst; cj.nblk[ns] = count / 2048;
      total += count / 2048; ++ns;
    };
    push(G_mi, gmib, MI_N * MI_N);
    push(G_dis, gdisb, DIS_N * DIS_N);
    push(mi_kan_Ws, wsb0, 256 * 24576);
    push(dis_kan_Ws, wsb1, 256 * 24576);
    push(mi_kan_Wb, wbb0, 256 * 3072);
    push(dis_kan_Wb, wbb1, 256 * 3072);
    push(mi_jk_W, jkwb0, 256 * 3840);
    push(dis_jk_W, jkwb1, 256 * 3840);
    push(mi_rW1, rw1b0, LL * 64 * 256);
    push(dis_rW1, rw1b1, LL * 64 * 256);
    push(mi_rW2, rw2b0, LL * 256 * 64);
    push(dis_rW2, rw2b1, LL * 256 * 64);
    push(lx_W1, lxw1b, 256 * 256);
    push(lx_W2, lxw2b, 128 * 256);
    push(lx_W3, lxw3b, 64 * 128);
    push(ly_W1, lyw1b, 256 * 256);
    push(ly_W2, lyw2b, 128 * 256);
    push(ly_W3, lyw3b, 64 * 128);
    push(ne_W, neb, 512 * 3072);
    push(he_W, heb, 512 * 3072);
    // mun/mue folded below (counts 64*512 each) -- need 22 slots; merge:
    cj.nseg = ns;
    cvt_f2b<<<dim3(total), B256, 0, stream>>>(cj);
    CvtJobs cj2{};
    cj2.src[0] = mun_W; cj2.dst[0] = munb; cj2.nblk[0] = (64 * 512) / 2048;
    cj2.src[1] = mue_W; cj2.dst[1] = mueb; cj2.nblk[1] = (64 * 512) / 2048;
    cj2.nseg = 2;
    cvt_f2b<<<dim3(32), B256, 0, stream>>>(cj2);
  }
  // 1) fastkan LN + bf16 copy of concat
  ln_silu<<<dim3(TOT_N), B256, 0, stream>>>(concat_mi, concat_dis, mi_kan_ln_g, mi_kan_ln_b,
                                            dis_kan_ln_g, dis_kan_ln_b, xn, cbf);
  // 2) W_eff for all layers/sides
  weff_kernel<<<dim3(2 * LL * 256), B256, 0, stream>>>(mi_W, mi_attn, dis_W, dis_attn, wefft);
  // 3) fastkan fused GEMM + combine -> e
  {
    FKP f0{xn, cbf, wsb0, wbb0, fkp, 0, 64};
    FKP f1{xn + (size_t)MI_N * DIN, cbf + (size_t)MI_N * DIN, wsb1, wbb1, fkp, MI_N, 32};
    fastkan_gemm<<<dim3(96, 2, 5), B256, 0, stream>>>(f0, f1, rbf_grid);
    fk_combine<<<dim3(TOT_N * HID / 256), B256, 0, stream>>>(fkp, mi_kan_bb, dis_kan_bb, e);
  }
  // 4) HGCN layers
  for (int l = 0; l < LL; ++l) {
    const u16* xc0 = (l == 0) ? e : jk + (size_t)(l - 1) * HID;
    const u16* xc1 = (l == 0) ? e + (size_t)MI_N * HID
                              : jk + (size_t)MI_N * LL * HID + (size_t)(l - 1) * HID;
    const int xlda = (l == 0) ? HID : LL * HID;
    GP a0{xc0, xlda, wefft + (size_t)l * 65536, 256, t1t, MI_N, nullptr, 256, 64};
    GP a1{xc1, xlda, wefft + ((size_t)LL + l) * 65536, 256, t1t + (size_t)HID * MI_N, DIS_N,
          nullptr, 256, 32};
    gemm_bt<0, 1, 0, 4><<<dim3(96, 4), B256, 0, stream>>>(a0, a1);
    GP h0{gmib, MI_N, t1t, MI_N, hout, HID, mi_bias + l * HID, MI_N, 64};
    GP h1{gdisb, DIS_N, t1t + (size_t)HID * MI_N, DIS_N, hout + (size_t)MI_N * HID, HID,
          dis_bias + l * HID, DIS_N, 32};
    gemm_bt<0, 0, 0, 4><<<dim3(96, 4), B256, 0, stream>>>(h0, h1);
    GP g0{hout, HID, rw1b0 + (size_t)l * 64 * HID, HID, g1b, 64, mi_rb1 + l * 64, HID, 64};
    GP g1{hout + (size_t)MI_N * HID, HID, rw1b1 + (size_t)l * 64 * HID, HID,
          g1b + (size_t)MI_N * 64, 64, dis_rb1 + l * 64, HID, 32};
    gemm_bt<1, 0, 0, 4><<<dim3(96, 1), B256, 0, stream>>>(g0, g1);
    GP s0{g1b, 64, rw2b0 + (size_t)l * HID * 64, 64, gateb, HID, mi_rb2 + l * HID, 64, 64};
    GP s1{g1b + (size_t)MI_N * 64, 64, rw2b1 + (size_t)l * HID * 64, 64,
          gateb + (size_t)MI_N * HID, HID, dis_rb2 + l * HID, 64, 32};
    gemm_bt<2, 0, 0, 4><<<dim3(96, 4), B256, 0, stream>>>(s0, s1);
    gate_ln<<<dim3(TOT_N), B256, 0, stream>>>(hout, gateb, mi_ln_g, mi_ln_b, dis_ln_g,
                                              dis_ln_b, jk, l);
  }
  // 5) jk projection
  {
    GP j0{jk, LL * HID, jkwb0, LL * HID, fb, HID, mi_jk_b, LL * HID, 64};
    GP j1{jk + (size_t)MI_N * LL * HID, LL * HID, jkwb1, LL * HID, fb + (size_t)MI_N * HID,
          HID, dis_jk_b, LL * HID, 32};
    gemm_bt<0, 0, 0, 4><<<dim3(96, 4), B256, 0, stream>>>(j0, j1);
  }
  // 6) mlp3
  {
    GP m0{fb, HID, lxw1b, HID, h1b, 256, lx_b1, HID, 64};
    GP m1{fb + (size_t)MI_N * HID, HID, lyw1b, HID, h1b + (size_t)MI_N * 256, 256, ly_b1,
          HID, 32};
    gemm_bt<1, 0, 0, 4><<<dim3(96, 4), B256, 0, stream>>>(m0, m1);
    GP n0{h1b, 256, lxw2b, 256, h2b, 128, lx_b2, 256, 64};
    GP n1{h1b + (size_t)MI_N * 256, 256, lyw2b, 256, h2b + (size_t)MI_N * 128, 128, ly_b2,
          256, 32};
    gemm_bt<1, 0, 0, 4><<<dim3(96, 2), B256, 0, stream>>>(n0, n1);
    GP o0{h2b, 128, lxw3b, 128, xyb, 64, lx_b3, 128, 64};
    GP o1{h2b + (size_t)MI_N * 128, 128, lyw3b, 128, xyb + (size_t)MI_N * 64, 64, ly_b3,
          128, 32};
    gemm_bt<1, 0, 0, 4><<<dim3(96, 1), B256, 0, stream>>>(o0, o1);
  }
  // 7) result_h = x @ y^T (f32)
  {
    GP r0{xyb, 64, xyb + (size_t)MI_N * 64, 64, rh, DIS_N, nullptr, 64, 64};
    gemm_bt<0, 0, 1, 4><<<dim3(64, 16), B256, 0, stream>>>(r0, r0);
  }
  // 8) encoders
  {
    GP e0{cbf, DIN, neb, DIN, zb, 512, ne_b, DIN, 64};
    GP e1{cbf + (size_t)MI_N * DIN, DIN, heb, DIN, zb + (size_t)MI_N * 512, 512, he_b, DIN,
          32};
    gemm_bt<1, 0, 0, 4><<<dim3(96, 8), B256, 0, stream>>>(e0, e1);
  }
  // 9) means
  {
    GP u0{zb, 512, munb, 512, zm, 64, mun_b, 512, 64};
    GP u1{zb + (size_t)MI_N * 512, 512, mueb, 512, zm + (size_t)MI_N * 64, 64, mue_b, 512,
          32};
    gemm_bt<0, 0, 0, 4><<<dim3(96, 1), B256, 0, stream>>>(u0, u1);
  }
  // 10) recon -> d_out second half (f32)
  {
    GP c0{zm, 64, zm + (size_t)MI_N * 64, 64, rec, DIS_N, nullptr, 64, 64};
    gemm_bt<0, 0, 1, 4><<<dim3(64, 16), B256, 0, stream>>>(c0, c0);
  }
  // 11) score
  final_combine<<<dim3(MI_N * DIS_N / 256), B256, 0, stream>>>(rh, outf);
}